// Round 3
// baseline (316.348 us; speedup 1.0000x reference)
//
#include <hip/hip_runtime.h>

// Problem constants (fixed by the reference).
#define BATCH   128
#define RANK    64
#define HIDDEN  4096
#define NADPT   256

// Per-block H chunk: grid.y = HIDDEN / HCHUNK = 4; 256 threads * 4 floats each.
#define HCHUNK  1024

__global__ __launch_bounds__(256) void PaddedLoraB_59459527246474_kernel(
    const float* __restrict__ y,      // [BATCH, RANK] f32 (harness upcasts f16->f32)
    const int*   __restrict__ wids,   // [BATCH]
    const float* __restrict__ loraB,  // [NADPT, RANK, HIDDEN] f32
    float*       __restrict__ out)    // [BATCH, HIDDEN] f32
{
    const int b   = blockIdx.x;
    const int wid = wids[b] & (NADPT - 1);   // clamp: OOB insurance only
    const int h0  = blockIdx.y * HCHUNK + threadIdx.x * 4;

    // Stage y[b,:] into LDS. All lanes read the same address per iteration
    // -> broadcast, no bank conflicts.
    __shared__ float ysh[RANK];
    if (threadIdx.x < RANK) {
        ysh[threadIdx.x] = y[b * RANK + threadIdx.x];
    }
    __syncthreads();

    const float* Bp = loraB + (size_t)wid * (RANK * HIDDEN) + h0;

    float acc0 = 0.f, acc1 = 0.f, acc2 = 0.f, acc3 = 0.f;

#pragma unroll 8
    for (int r = 0; r < RANK; ++r) {
        const float4 v = *(const float4*)(Bp + (size_t)r * HIDDEN);  // 16B/lane coalesced
        const float yv = ysh[r];
        acc0 = fmaf(yv, v.x, acc0);
        acc1 = fmaf(yv, v.y, acc1);
        acc2 = fmaf(yv, v.z, acc2);
        acc3 = fmaf(yv, v.w, acc3);
    }

    float4 o;
    o.x = 2.f * acc0;
    o.y = 2.f * acc1;
    o.z = 2.f * acc2;
    o.w = 2.f * acc3;
    *(float4*)(out + (size_t)b * HIDDEN + h0) = o;
}

extern "C" void kernel_launch(void* const* d_in, const int* in_sizes, int n_in,
                              void* d_out, int out_size, void* d_ws, size_t ws_size,
                              hipStream_t stream) {
    // Bind inputs by element count (distinct sizes): y=8192, wids=128,
    // lora_B=67108864. Dtypes: reference f16 tensors are provided as f32 by
    // the harness (only bf16/f32/int32 decode paths exist); round-1/2's
    // bf16-bits interpretation produced 2.2e19 garbage = f32-read-as-bf16.
    const float* y     = nullptr;
    const int*   wids  = nullptr;
    const float* loraB = nullptr;
    for (int i = 0; i < n_in; ++i) {
        if (in_sizes[i] == BATCH * RANK)               y     = (const float*)d_in[i];
        else if (in_sizes[i] == BATCH)                 wids  = (const int*)d_in[i];
        else if (in_sizes[i] == NADPT * RANK * HIDDEN) loraB = (const float*)d_in[i];
    }
    float* out = (float*)d_out;  // [128,1,4096] f32

    dim3 grid(BATCH, HIDDEN / HCHUNK, 1);  // (128, 4)
    dim3 block(256, 1, 1);
    PaddedLoraB_59459527246474_kernel<<<grid, block, 0, stream>>>(y, wids, loraB, out);
}